// Round 4
// baseline (212.407 us; speedup 1.0000x reference)
//
#include <hip/hip_runtime.h>

// YOLOv1 loss, faithful to the reference (including the in-place corner bug).
// R4: persistent grid-stride blocks (5/CU) + software pipeline: next tile's
// T-staging (LDS) and P-loads (regs) overlap current tile's compute. Per-thread
// accumulators across tiles -> one reduction + one float4 store per block
// (was: per tile). Removes block churn and the per-tile 24-deep shfl chain.

constexpr int   BS   = 256;            // cells per tile (threads per block)
constexpr int   NC   = 16384 * 7 * 7;  // 802816 cells
constexpr int   NB   = NC / BS;        // 3136 tiles
constexpr int   NBLK = 1280;           // persistent blocks: 5 per CU
constexpr float CELL = 1.0f / 7.0f;
constexpr float LC   = 5.0f;
constexpr float LN   = 0.5f;

__device__ __forceinline__ void load_p10(float* pv, const float* prow) {
    #pragma unroll
    for (int j = 0; j < 5; ++j) {
        float2 v = reinterpret_cast<const float2*>(prow)[j];
        pv[2 * j] = v.x; pv[2 * j + 1] = v.y;
    }
}

__device__ __forceinline__ void stage_T(float* sT, const float* Tbase, int tid) {
    const float4* g4 = reinterpret_cast<const float4*>(Tbase);
    float4* s4 = reinterpret_cast<float4*>(sT);
    constexpr int NV4 = BS * 30 / 4;  // 1920
    #pragma unroll
    for (int k = 0; k < (NV4 + BS - 1) / BS; ++k) {
        int idx = k * BS + tid;
        if (idx < NV4) s4[idx] = g4[idx];
    }
}

__launch_bounds__(BS, 5)
__global__ void yolo_partial(const float* __restrict__ P, const float* __restrict__ T,
                             float4* __restrict__ ws)
{
    __shared__ float sT[BS * 30];          // 30720 B -> 5 blocks/CU
    __shared__ float red[4][BS / 64];

    const int tid = threadIdx.x;

    float a_cls = 0.f, a_conf = 0.f, a_cw = 0.f, a_noobj = 0.f;

    // ---- prologue: stage first tile ----
    int tile = blockIdx.x;                 // NBLK <= NB, always valid
    size_t base = (size_t)tile * (BS * 30);
    float pv[10];
    load_p10(pv, P + base + (size_t)tid * 30);
    stage_T(sT, T + base, tid);
    __syncthreads();

    float tv[30];
    {
        const float* tt = sT + tid * 30;
        #pragma unroll
        for (int j = 0; j < 15; ++j) {
            float2 v = reinterpret_cast<const float2*>(tt)[j];
            tv[2 * j] = v.x; tv[2 * j + 1] = v.y;
        }
    }
    __syncthreads();                       // LDS free for next stage

    while (true) {
        // ---- issue next tile's loads (overlap with compute below) ----
        const int next = tile + NBLK;
        const bool has_next = next < NB;
        float pvn[10];
        if (has_next) {
            size_t nbase = (size_t)next * (BS * 30);
            load_p10(pvn, P + nbase + (size_t)tid * 30);
            stage_T(sT, T + nbase, tid);
        }

        // ---- class-column argmax + early dynamic gather p[kc] ----
        int kc = 10;
        float best = tv[10];
        #pragma unroll
        for (int k = 11; k < 30; ++k) {
            if (tv[k] > best) { best = tv[k]; kc = k; }
        }
        float pk = P[base + (size_t)tid * 30 + kc];

        // ---- per-cell loss terms (faithful to reference) ----
        const float t4 = tv[4];
        const float obj   = (t4 == 1.0f) ? 1.0f : 0.0f;
        const float noobj = (t4 == 0.0f) ? 1.0f : 0.0f;

        float d4 = pv[4] - t4;
        float d9 = pv[9] - tv[9];
        a_noobj += noobj * (d4 * d4 + d9 * d9);

        // target corners (faithful bug: x2 uses already-updated x1)
        float tw2 = tv[2] * tv[2], th2 = tv[3] * tv[3];
        float tx1 = tv[0] * CELL - 0.5f * tw2;
        float tx2 = tx1 * CELL + 0.5f * tw2;
        float ty1 = tv[1] * CELL - 0.5f * th2;
        float ty2 = ty1 * CELL + 0.5f * th2;
        float area_t = (tx2 - tx1) * (ty2 - ty1);

        float iou0, iou1;
        #pragma unroll
        for (int b = 0; b < 2; ++b) {
            float bw2 = pv[5 * b + 2] * pv[5 * b + 2];
            float bh2 = pv[5 * b + 3] * pv[5 * b + 3];
            float px1 = pv[5 * b + 0] * CELL - 0.5f * bw2;
            float px2 = px1 * CELL + 0.5f * bw2;
            float py1 = pv[5 * b + 1] * CELL - 0.5f * bh2;
            float py2 = py1 * CELL + 0.5f * bh2;
            float ltx = fmaxf(px1, tx1), lty = fmaxf(py1, ty1);
            float rbx = fminf(px2, tx2), rby = fminf(py2, ty2);
            float inter = fmaxf(rbx - ltx, 0.0f) * fmaxf(rby - lty, 0.0f);
            float area_p = (px2 - px1) * (py2 - py1);
            float iou = inter / (area_p + area_t - inter);
            if (b == 0) iou0 = iou; else iou1 = iou;
        }
        const bool b1 = (iou1 > iou0);     // jnp.argmax: first on ties

        float cpx = b1 ? pv[5] : pv[0], ctx = b1 ? tv[5] : tv[0];
        float cpy = b1 ? pv[6] : pv[1], cty = b1 ? tv[6] : tv[1];
        float cpw = b1 ? pv[7] : pv[2], ctw = b1 ? tv[7] : tv[2];
        float cph = b1 ? pv[8] : pv[3], cth = b1 ? tv[8] : tv[3];
        float cpc = b1 ? pv[9] : pv[4], ctc = b1 ? tv[9] : tv[4];

        float dx = cpx - ctx, dy = cpy - cty;
        float dw = cpw - ctw, dh = cph - cth;
        a_cw   += obj * (dx * dx + dy * dy + dw * dw + dh * dh);
        float dc = cpc - ctc;
        a_conf += obj * dc * dc;
        float dk = pk - best;
        a_cls  += obj * dk * dk;

        if (!has_next) break;

        // ---- consume next tile: LDS -> regs, then release LDS ----
        __syncthreads();                   // staging complete
        {
            const float* tt = sT + tid * 30;
            #pragma unroll
            for (int j = 0; j < 15; ++j) {
                float2 v = reinterpret_cast<const float2*>(tt)[j];
                tv[2 * j] = v.x; tv[2 * j + 1] = v.y;
            }
        }
        __syncthreads();                   // LDS free again
        #pragma unroll
        for (int j = 0; j < 10; ++j) pv[j] = pvn[j];
        tile = next;
        base = (size_t)tile * (BS * 30);
    }

    // ---- once-per-block reduction: wave -> block -> one float4 store ----
    float vals[4] = { a_cls, a_conf, a_cw, a_noobj };
    #pragma unroll
    for (int c = 0; c < 4; ++c) {
        float v = vals[c];
        #pragma unroll
        for (int off = 32; off > 0; off >>= 1)
            v += __shfl_down(v, off, 64);
        if ((tid & 63) == 0) red[c][tid >> 6] = v;
    }
    __syncthreads();
    if (tid == 0) {
        float4 s;
        s.x = red[0][0] + red[0][1] + red[0][2] + red[0][3];
        s.y = red[1][0] + red[1][1] + red[1][2] + red[1][3];
        s.z = red[2][0] + red[2][1] + red[2][2] + red[2][3];
        s.w = red[3][0] + red[3][1] + red[3][2] + red[3][3];
        ws[blockIdx.x] = s;                // unique cache line per block
    }
}

__launch_bounds__(256, 1)
__global__ void yolo_reduce(const float4* __restrict__ ws, float* __restrict__ out)
{
    __shared__ float red[4][4];
    const int tid = threadIdx.x;

    float s0 = 0.f, s1 = 0.f, s2 = 0.f, s3 = 0.f;
    for (int b = tid; b < NBLK; b += 256) {     // coalesced float4 stream
        float4 v = ws[b];
        s0 += v.x; s1 += v.y; s2 += v.z; s3 += v.w;
    }
    float vals[4] = { s0, s1, s2, s3 };
    #pragma unroll
    for (int c = 0; c < 4; ++c) {
        float v = vals[c];
        #pragma unroll
        for (int off = 32; off > 0; off >>= 1)
            v += __shfl_down(v, off, 64);
        if ((tid & 63) == 0) red[c][tid >> 6] = v;
    }
    __syncthreads();
    if (tid == 0) {
        float t0 = red[0][0] + red[0][1] + red[0][2] + red[0][3];
        float t1 = red[1][0] + red[1][1] + red[1][2] + red[1][3];
        float t2 = red[2][0] + red[2][1] + red[2][2] + red[2][3];
        float t3 = red[3][0] + red[3][1] + red[3][2] + red[3][3];
        out[0] = LC * t0;                              // cls_loss
        out[1] = LC * t1;                              // conf_loss
        out[2] = LC * t2;                              // center+wh
        out[3] = LN * t3 + LC * (t0 + t1 + t2);        // total
    }
}

extern "C" void kernel_launch(void* const* d_in, const int* in_sizes, int n_in,
                              void* d_out, int out_size, void* d_ws, size_t ws_size,
                              hipStream_t stream) {
    const float* P = (const float*)d_in[0];
    const float* T = (const float*)d_in[1];
    float* out = (float*)d_out;
    float4* ws = (float4*)d_ws;          // NBLK * 16 B = 20480 B of scratch

    yolo_partial<<<NBLK, BS, 0, stream>>>(P, T, ws);
    yolo_reduce<<<1, 256, 0, stream>>>(ws, out);
}

// Round 5
// 207.520 us; speedup vs baseline: 1.0235x; 1.0235x over previous
//
#include <hip/hip_runtime.h>

// YOLOv1 loss, faithful to the reference (including the in-place corner bug).
// R5: all global traffic is coalesced float4; single-wave workgroups (64 thr)
// stage P+T slabs (7680 B each) into private LDS -> no inter-wave barriers,
// no strided global loads, and the p[kcol] gather becomes a ds_read.
// Grid = 2560 (10 blocks/CU, LDS 15360 B each), each wave strides ~5 tiles
// with register accumulators; one float4 partial per block + tiny reduce.

constexpr int   WSZ  = 64;              // threads per block = 1 wave = cells/tile
constexpr int   NC   = 16384 * 7 * 7;   // 802816 cells
constexpr int   NT   = NC / WSZ;        // 12544 tiles
constexpr int   GRID = 2560;            // 10 single-wave blocks per CU
constexpr float CELL = 1.0f / 7.0f;
constexpr float LC   = 5.0f;
constexpr float LN   = 0.5f;

__launch_bounds__(WSZ, 2)
__global__ void yolo_partial(const float* __restrict__ P, const float* __restrict__ T,
                             float4* __restrict__ ws)
{
    __shared__ float sP[WSZ * 30];      // 7680 B
    __shared__ float sT[WSZ * 30];      // 7680 B  -> 15360 B/block, 10 blocks/CU

    const int lane = threadIdx.x;
    float a_cls = 0.f, a_conf = 0.f, a_cw = 0.f, a_noobj = 0.f;

    for (int tile = blockIdx.x; tile < NT; tile += GRID) {
        const size_t base = (size_t)tile * (WSZ * 30);

        // ---- fully coalesced float4 staging of both 1920-float slabs ----
        const float4* gP = reinterpret_cast<const float4*>(P + base);
        const float4* gT = reinterpret_cast<const float4*>(T + base);
        float4* s4P = reinterpret_cast<float4*>(sP);
        float4* s4T = reinterpret_cast<float4*>(sT);
        constexpr int NV4 = WSZ * 30 / 4;   // 480 float4 per slab
        #pragma unroll
        for (int k = 0; k < 8; ++k) {
            int idx = k * WSZ + lane;
            if (idx < NV4) { s4P[idx] = gP[idx]; s4T[idx] = gT[idx]; }
        }
        __syncthreads();   // single wave: compiles to waitcnt, no convoy

        // ---- lane reads its own row from LDS ----
        const float* tt = sT + lane * 30;
        const float* tp = sP + lane * 30;
        float tv[30];
        #pragma unroll
        for (int j = 0; j < 15; ++j) {
            float2 v = reinterpret_cast<const float2*>(tt)[j];
            tv[2 * j] = v.x; tv[2 * j + 1] = v.y;
        }
        float pv[10];
        #pragma unroll
        for (int j = 0; j < 5; ++j) {
            float2 v = reinterpret_cast<const float2*>(tp)[j];
            pv[2 * j] = v.x; pv[2 * j + 1] = v.y;
        }

        // class column: argmax over t[10:30], first occurrence (strict >)
        int kc = 10;
        float best = tv[10];
        #pragma unroll
        for (int k = 11; k < 30; ++k) {
            if (tv[k] > best) { best = tv[k]; kc = k; }
        }
        float pk = tp[kc];               // dynamic ds_read, ~cheap vs global

        const float t4 = tv[4];
        const float obj   = (t4 == 1.0f) ? 1.0f : 0.0f;
        const float noobj = (t4 == 0.0f) ? 1.0f : 0.0f;

        float d4 = pv[4] - t4;
        float d9 = pv[9] - tv[9];
        a_noobj += noobj * (d4 * d4 + d9 * d9);

        // target corners (faithful bug: x2 uses already-updated x1)
        float tw2 = tv[2] * tv[2], th2 = tv[3] * tv[3];
        float tx1 = tv[0] * CELL - 0.5f * tw2;
        float tx2 = tx1 * CELL + 0.5f * tw2;
        float ty1 = tv[1] * CELL - 0.5f * th2;
        float ty2 = ty1 * CELL + 0.5f * th2;
        float area_t = (tx2 - tx1) * (ty2 - ty1);

        float iou0, iou1;
        #pragma unroll
        for (int b = 0; b < 2; ++b) {
            float bw2 = pv[5 * b + 2] * pv[5 * b + 2];
            float bh2 = pv[5 * b + 3] * pv[5 * b + 3];
            float px1 = pv[5 * b + 0] * CELL - 0.5f * bw2;
            float px2 = px1 * CELL + 0.5f * bw2;
            float py1 = pv[5 * b + 1] * CELL - 0.5f * bh2;
            float py2 = py1 * CELL + 0.5f * bh2;
            float ltx = fmaxf(px1, tx1), lty = fmaxf(py1, ty1);
            float rbx = fminf(px2, tx2), rby = fminf(py2, ty2);
            float inter = fmaxf(rbx - ltx, 0.0f) * fmaxf(rby - lty, 0.0f);
            float area_p = (px2 - px1) * (py2 - py1);
            float iou = inter / (area_p + area_t - inter);
            if (b == 0) iou0 = iou; else iou1 = iou;
        }
        const bool b1 = (iou1 > iou0);   // jnp.argmax: first on ties

        float cpx = b1 ? pv[5] : pv[0], ctx = b1 ? tv[5] : tv[0];
        float cpy = b1 ? pv[6] : pv[1], cty = b1 ? tv[6] : tv[1];
        float cpw = b1 ? pv[7] : pv[2], ctw = b1 ? tv[7] : tv[2];
        float cph = b1 ? pv[8] : pv[3], cth = b1 ? tv[8] : tv[3];
        float cpc = b1 ? pv[9] : pv[4], ctc = b1 ? tv[9] : tv[4];

        float dx = cpx - ctx, dy = cpy - cty;
        float dw = cpw - ctw, dh = cph - cth;
        a_cw   += obj * (dx * dx + dy * dy + dw * dw + dh * dh);
        float dc = cpc - ctc;
        a_conf += obj * dc * dc;
        float dk = pk - best;
        a_cls  += obj * dk * dk;

        __syncthreads();                 // LDS reads done before next staging
    }

    // ---- wave reduction (6 rounds x 4 channels), one float4 store ----
    float vals[4] = { a_cls, a_conf, a_cw, a_noobj };
    #pragma unroll
    for (int c = 0; c < 4; ++c) {
        #pragma unroll
        for (int off = 32; off > 0; off >>= 1)
            vals[c] += __shfl_down(vals[c], off, 64);
    }
    if (lane == 0)
        ws[blockIdx.x] = make_float4(vals[0], vals[1], vals[2], vals[3]);
}

__launch_bounds__(1024, 1)
__global__ void yolo_reduce(const float4* __restrict__ ws, float* __restrict__ out)
{
    __shared__ float red[4][16];
    const int tid = threadIdx.x;

    float s0 = 0.f, s1 = 0.f, s2 = 0.f, s3 = 0.f;
    for (int b = tid; b < GRID; b += 1024) {    // coalesced float4 stream
        float4 v = ws[b];
        s0 += v.x; s1 += v.y; s2 += v.z; s3 += v.w;
    }
    float vals[4] = { s0, s1, s2, s3 };
    #pragma unroll
    for (int c = 0; c < 4; ++c) {
        #pragma unroll
        for (int off = 32; off > 0; off >>= 1)
            vals[c] += __shfl_down(vals[c], off, 64);
        if ((tid & 63) == 0) red[c][tid >> 6] = vals[c];
    }
    __syncthreads();
    if (tid == 0) {
        float t0 = 0.f, t1 = 0.f, t2 = 0.f, t3 = 0.f;
        #pragma unroll
        for (int w = 0; w < 16; ++w) {
            t0 += red[0][w]; t1 += red[1][w]; t2 += red[2][w]; t3 += red[3][w];
        }
        out[0] = LC * t0;                              // cls_loss
        out[1] = LC * t1;                              // conf_loss
        out[2] = LC * t2;                              // center+wh
        out[3] = LN * t3 + LC * (t0 + t1 + t2);        // total
    }
}

extern "C" void kernel_launch(void* const* d_in, const int* in_sizes, int n_in,
                              void* d_out, int out_size, void* d_ws, size_t ws_size,
                              hipStream_t stream) {
    const float* P = (const float*)d_in[0];
    const float* T = (const float*)d_in[1];
    float* out = (float*)d_out;
    float4* ws = (float4*)d_ws;          // GRID * 16 B = 40960 B of scratch

    yolo_partial<<<GRID, WSZ, 0, stream>>>(P, T, ws);
    yolo_reduce<<<1, 1024, 0, stream>>>(ws, out);
}

// Round 6
// 207.290 us; speedup vs baseline: 1.0247x; 1.0011x over previous
//
#include <hip/hip_runtime.h>

// YOLOv1 loss, faithful to the reference (including the in-place corner bug).
// R6: two levers vs R5 -- (1) waves: stage only T in LDS (7680 B/block) so 16
// single-wave blocks fit per CU (R5's 15360 B capped at 10); (2) bytes: P is
// never staged -- cols 0..9 via five float2 strided loads (L1 merges lines),
// p[kcol] via one dependent 8-B gather after the argmax. Demand drops
// ~192.7 -> ~150 MB. Delivered-BW model: time = bytes / (waves * per-wave rate).

constexpr int   WSZ  = 64;              // threads per block = 1 wave = cells/tile
constexpr int   NC   = 16384 * 7 * 7;   // 802816 cells
constexpr int   NT   = NC / WSZ;        // 12544 tiles
constexpr int   GRID = 4096;            // 16 single-wave blocks per CU
constexpr float CELL = 1.0f / 7.0f;
constexpr float LC   = 5.0f;
constexpr float LN   = 0.5f;

__launch_bounds__(WSZ, 4)               // 4 waves/EU -> 16 blocks/CU resident
__global__ void yolo_partial(const float* __restrict__ P, const float* __restrict__ T,
                             float4* __restrict__ ws)
{
    __shared__ float sT[WSZ * 30];      // 7680 B -> LDS allows 20, WG cap ~16
    const int lane = threadIdx.x;
    float a_cls = 0.f, a_conf = 0.f, a_cw = 0.f, a_noobj = 0.f;

    for (int tile = blockIdx.x; tile < NT; tile += GRID) {
        const size_t base = (size_t)tile * (WSZ * 30);

        // ---- coalesced float4 staging of the T slab (480 float4) ----
        const float4* gT = reinterpret_cast<const float4*>(T + base);
        float4* s4 = reinterpret_cast<float4*>(sT);
        #pragma unroll
        for (int k = 0; k < 8; ++k) {
            int idx = k * WSZ + lane;
            if (idx < 480) s4[idx] = gT[idx];
        }

        // ---- per-thread P cols 0..9: five float2 (row stride 120 B, 8-B aligned),
        //      issued in the same vmcnt batch as the staging loads ----
        const float* prow = P + base + (size_t)lane * 30;
        float pv[10];
        #pragma unroll
        for (int j = 0; j < 5; ++j) {
            float2 v = reinterpret_cast<const float2*>(prow)[j];
            pv[2 * j] = v.x; pv[2 * j + 1] = v.y;
        }
        __syncthreads();                 // single wave: waitcnt, no convoy

        // ---- lane's T row from LDS ----
        const float* tt = sT + lane * 30;
        float tv[30];
        #pragma unroll
        for (int j = 0; j < 15; ++j) {
            float2 v = reinterpret_cast<const float2*>(tt)[j];
            tv[2 * j] = v.x; tv[2 * j + 1] = v.y;
        }

        // class column: argmax over t[10:30], first occurrence (strict >)
        int kc = 10;
        float best = tv[10];
        #pragma unroll
        for (int k = 11; k < 30; ++k) {
            if (tv[k] > best) { best = tv[k]; kc = k; }
        }
        // dependent 8-B gather for p[kc] (kc in [10,30)); issue early
        float2 pg = *reinterpret_cast<const float2*>(prow + (kc & ~1));
        float pk = (kc & 1) ? pg.y : pg.x;

        const float t4 = tv[4];
        const float obj   = (t4 == 1.0f) ? 1.0f : 0.0f;
        const float noobj = (t4 == 0.0f) ? 1.0f : 0.0f;

        float d4 = pv[4] - t4;
        float d9 = pv[9] - tv[9];
        a_noobj += noobj * (d4 * d4 + d9 * d9);

        // target corners (faithful bug: x2 uses already-updated x1)
        float tw2 = tv[2] * tv[2], th2 = tv[3] * tv[3];
        float tx1 = tv[0] * CELL - 0.5f * tw2;
        float tx2 = tx1 * CELL + 0.5f * tw2;
        float ty1 = tv[1] * CELL - 0.5f * th2;
        float ty2 = ty1 * CELL + 0.5f * th2;
        float area_t = (tx2 - tx1) * (ty2 - ty1);

        float iou0, iou1;
        #pragma unroll
        for (int b = 0; b < 2; ++b) {
            float bw2 = pv[5 * b + 2] * pv[5 * b + 2];
            float bh2 = pv[5 * b + 3] * pv[5 * b + 3];
            float px1 = pv[5 * b + 0] * CELL - 0.5f * bw2;
            float px2 = px1 * CELL + 0.5f * bw2;
            float py1 = pv[5 * b + 1] * CELL - 0.5f * bh2;
            float py2 = py1 * CELL + 0.5f * bh2;
            float ltx = fmaxf(px1, tx1), lty = fmaxf(py1, ty1);
            float rbx = fminf(px2, tx2), rby = fminf(py2, ty2);
            float inter = fmaxf(rbx - ltx, 0.0f) * fmaxf(rby - lty, 0.0f);
            float area_p = (px2 - px1) * (py2 - py1);
            float iou = inter / (area_p + area_t - inter);
            if (b == 0) iou0 = iou; else iou1 = iou;
        }
        const bool b1 = (iou1 > iou0);   // jnp.argmax: first on ties

        float cpx = b1 ? pv[5] : pv[0], ctx = b1 ? tv[5] : tv[0];
        float cpy = b1 ? pv[6] : pv[1], cty = b1 ? tv[6] : tv[1];
        float cpw = b1 ? pv[7] : pv[2], ctw = b1 ? tv[7] : tv[2];
        float cph = b1 ? pv[8] : pv[3], cth = b1 ? tv[8] : tv[3];
        float cpc = b1 ? pv[9] : pv[4], ctc = b1 ? tv[9] : tv[4];

        float dx = cpx - ctx, dy = cpy - cty;
        float dw = cpw - ctw, dh = cph - cth;
        a_cw   += obj * (dx * dx + dy * dy + dw * dw + dh * dh);
        float dc = cpc - ctc;
        a_conf += obj * dc * dc;
        float dk = pk - best;
        a_cls  += obj * dk * dk;

        __syncthreads();                 // LDS consumed before next staging
    }

    // ---- wave reduction, one float4 store per block ----
    float vals[4] = { a_cls, a_conf, a_cw, a_noobj };
    #pragma unroll
    for (int c = 0; c < 4; ++c) {
        #pragma unroll
        for (int off = 32; off > 0; off >>= 1)
            vals[c] += __shfl_down(vals[c], off, 64);
    }
    if (lane == 0)
        ws[blockIdx.x] = make_float4(vals[0], vals[1], vals[2], vals[3]);
}

__launch_bounds__(1024, 1)
__global__ void yolo_reduce(const float4* __restrict__ ws, float* __restrict__ out)
{
    __shared__ float red[4][16];
    const int tid = threadIdx.x;

    float s0 = 0.f, s1 = 0.f, s2 = 0.f, s3 = 0.f;
    for (int b = tid; b < GRID; b += 1024) {    // coalesced float4 stream
        float4 v = ws[b];
        s0 += v.x; s1 += v.y; s2 += v.z; s3 += v.w;
    }
    float vals[4] = { s0, s1, s2, s3 };
    #pragma unroll
    for (int c = 0; c < 4; ++c) {
        #pragma unroll
        for (int off = 32; off > 0; off >>= 1)
            vals[c] += __shfl_down(vals[c], off, 64);
        if ((tid & 63) == 0) red[c][tid >> 6] = vals[c];
    }
    __syncthreads();
    if (tid == 0) {
        float t0 = 0.f, t1 = 0.f, t2 = 0.f, t3 = 0.f;
        #pragma unroll
        for (int w = 0; w < 16; ++w) {
            t0 += red[0][w]; t1 += red[1][w]; t2 += red[2][w]; t3 += red[3][w];
        }
        out[0] = LC * t0;                              // cls_loss
        out[1] = LC * t1;                              // conf_loss
        out[2] = LC * t2;                              // center+wh
        out[3] = LN * t3 + LC * (t0 + t1 + t2);        // total
    }
}

extern "C" void kernel_launch(void* const* d_in, const int* in_sizes, int n_in,
                              void* d_out, int out_size, void* d_ws, size_t ws_size,
                              hipStream_t stream) {
    const float* P = (const float*)d_in[0];
    const float* T = (const float*)d_in[1];
    float* out = (float*)d_out;
    float4* ws = (float4*)d_ws;          // GRID * 16 B = 65536 B of scratch

    yolo_partial<<<GRID, WSZ, 0, stream>>>(P, T, ws);
    yolo_reduce<<<1, 1024, 0, stream>>>(ws, out);
}